// Round 2
// baseline (474.996 us; speedup 1.0000x reference)
//
#include <hip/hip_runtime.h>
#include <math.h>

// Fastfood layer, DPP-FWHT version.
//
// Wave = 64 lanes = 4 row-slots (r = lane>>4), 16 lanes per row (s = lane&15).
// Each lane holds 64 consecutive elements of its row: i = s*64 + k, k=0..63.
// FWHT-1024: bits 0-5 of i are in-register butterflies; bits 6-9 are lane bits
// 0-3, done with DPP (quad_perm / half_mirror / row_ror:8) -- pure VALU,
// nothing on the DS pipe. DS pipe only carries the permutation gather
// (bank-padded stride-65 layout: 2 lanes/bank = conflict-free).

template <int CTRL>
__device__ __forceinline__ float dpp_f(float x) {
    return __int_as_float(
        __builtin_amdgcn_mov_dpp(__float_as_int(x), CTRL, 0xF, 0xF, true));
}

#define DPP_XOR1 0xB1   // quad_perm [1,0,3,2]
#define DPP_XOR2 0x4E   // quad_perm [2,3,0,1]
#define DPP_XOR3 0x1B   // quad_perm [3,2,1,0]
#define DPP_HMIR 0x141  // row_half_mirror: lane ^ 7
#define DPP_ROR8 0x128  // row_ror:8 == lane ^ 8 within row-of-16

__device__ __forceinline__ void fwht1024(float v[64], float sg0, float sg1,
                                         float sg2, float sg3) {
    // Stages on bits 0-5 (register index k), h = 1..32
#pragma unroll
    for (int h = 1; h < 64; h <<= 1) {
#pragma unroll
        for (int k = 0; k < 64; ++k) {
            if (!(k & h)) {
                float a = v[k], b = v[k ^ h];
                v[k] = a + b;
                v[k ^ h] = a - b;
            }
        }
    }
    // Stage bit 6: partner = lane^1. result = fma(v, sign, partner)
#pragma unroll
    for (int k = 0; k < 64; ++k) v[k] = fmaf(v[k], sg0, dpp_f<DPP_XOR1>(v[k]));
    // Stage bit 7: lane^2
#pragma unroll
    for (int k = 0; k < 64; ++k) v[k] = fmaf(v[k], sg1, dpp_f<DPP_XOR2>(v[k]));
    // Stage bit 8: lane^4 = (lane^7)^3
#pragma unroll
    for (int k = 0; k < 64; ++k)
        v[k] = fmaf(v[k], sg2, dpp_f<DPP_XOR3>(dpp_f<DPP_HMIR>(v[k])));
    // Stage bit 9: lane^8 via row_ror:8
#pragma unroll
    for (int k = 0; k < 64; ++k) v[k] = fmaf(v[k], sg3, dpp_f<DPP_ROR8>(v[k]));
}

__global__ __launch_bounds__(64) void fastfood_kernel(
    const float* __restrict__ x, const float* __restrict__ B,
    const float* __restrict__ G, const float* __restrict__ S,
    const int* __restrict__ P, const float* __restrict__ u_rand,
    float* __restrict__ out)
{
    __shared__ float lds[4 * 1040];  // 4 row-slots, 16 slices * 65 words each
    const int lane = threadIdx.x;
    const int r = lane >> 4, s = lane & 15;
    const int row = blockIdx.x * 4 + r;
    const int m0 = blockIdx.y * 4;   // two m-halves per row-group

    const float sg0 = (lane & 1) ? -1.f : 1.f;
    const float sg1 = (lane & 2) ? -1.f : 1.f;
    const float sg2 = (lane & 4) ? -1.f : 1.f;
    const float sg3 = (lane & 8) ? -1.f : 1.f;

    float* wbase = lds + r * 1040 + s * 65;  // this lane's 64-elem slice (+pad)
    float* rbase = lds + r * 1040;           // row-slot base for the gather

    const float c_arg = 0.03125f * 0.15915494309189535f;  // (1/32)*(1/2pi)
    const float c_amp = 0.015625f;                        // sqrt(2/8192)

#pragma unroll 1
    for (int mm = 0; mm < 4; ++mm) {
        const int m = m0 + mm;
        const int mo = m * 1024 + s * 64;
        float v[64];

        // v = x * B[m]   (16 float4 loads each, fully unrolled)
        {
            const float4* x4 = (const float4*)(x + (size_t)row * 1024 + s * 64);
            const float4* B4 = (const float4*)(B + mo);
#pragma unroll
            for (int j = 0; j < 16; ++j) {
                float4 xt = x4[j], bt = B4[j];
                v[4 * j + 0] = xt.x * bt.x;
                v[4 * j + 1] = xt.y * bt.y;
                v[4 * j + 2] = xt.z * bt.z;
                v[4 * j + 3] = xt.w * bt.w;
            }
        }

        fwht1024(v, sg0, sg1, sg2, sg3);

        // Stage to LDS, padded layout: element i at word (i>>6)*65 + (i&63)
        // = i + (i>>6). Banks: (16r + s + k) % 32 -> 2 lanes/bank, free.
#pragma unroll
        for (int k = 0; k < 64; ++k) wbase[k] = v[k];

        // Gather with P, multiply by G (single wave: DS ops in order, no barrier)
        {
            const int4*   P4 = (const int4*)(P + mo);
            const float4* G4 = (const float4*)(G + mo);
#pragma unroll
            for (int j = 0; j < 16; ++j) {
                int4 p = P4[j];
                float4 g = G4[j];
                v[4 * j + 0] = rbase[p.x + (p.x >> 6)] * g.x;
                v[4 * j + 1] = rbase[p.y + (p.y >> 6)] * g.y;
                v[4 * j + 2] = rbase[p.z + (p.z >> 6)] * g.z;
                v[4 * j + 3] = rbase[p.w + (p.w >> 6)] * g.w;
            }
        }

        fwht1024(v, sg0, sg1, sg2, sg3);

        // Epilogue: cos( (1/32)*S*v + 2*pi*u ) * (1/64), via revolutions
        {
            const float4* S4 = (const float4*)(S + mo);
            const float4* U4 = (const float4*)(u_rand + mo);
            float4* o4 = (float4*)(out + (size_t)row * 8192 + mo);
#pragma unroll
            for (int j = 0; j < 16; ++j) {
                float4 sv = S4[j], uv = U4[j], rr;
                float s0 = sv.x * c_arg, s1 = sv.y * c_arg;
                float s2 = sv.z * c_arg, s3 = sv.w * c_arg;
                rr.x = __builtin_amdgcn_cosf(__builtin_amdgcn_fractf(
                           fmaf(v[4 * j + 0], s0, uv.x))) * c_amp;
                rr.y = __builtin_amdgcn_cosf(__builtin_amdgcn_fractf(
                           fmaf(v[4 * j + 1], s1, uv.y))) * c_amp;
                rr.z = __builtin_amdgcn_cosf(__builtin_amdgcn_fractf(
                           fmaf(v[4 * j + 2], s2, uv.z))) * c_amp;
                rr.w = __builtin_amdgcn_cosf(__builtin_amdgcn_fractf(
                           fmaf(v[4 * j + 3], s3, uv.w))) * c_amp;
                o4[j] = rr;
            }
        }
    }
}

extern "C" void kernel_launch(void* const* d_in, const int* in_sizes, int n_in,
                              void* d_out, int out_size, void* d_ws, size_t ws_size,
                              hipStream_t stream) {
    const float* x = (const float*)d_in[0];
    const float* B = (const float*)d_in[1];
    const float* G = (const float*)d_in[2];
    const float* S = (const float*)d_in[3];
    const int*   P = (const int*)d_in[4];
    const float* u = (const float*)d_in[5];
    float* out = (float*)d_out;

    dim3 grid(2048, 2), block(64);
    hipLaunchKernelGGL(fastfood_kernel, grid, block, 0, stream,
                       x, B, G, S, P, u, out);
}

// Round 3
// 366.786 us; speedup vs baseline: 1.2950x; 1.2950x over previous
//
#include <hip/hip_runtime.h>
#include <math.h>

// Fastfood layer, round 3: occupancy-first DPP+transpose FWHT.
//
// One wave per row, 16 consecutive elements per lane (L1: i = 16*lane + k).
// FWHT-1024 stages:
//   bits 0-3 : in-register butterflies (k index)
//   bits 4-7 : lane bits 0-3 via DPP (xor1=quad_perm B1, xor2=4E,
//              xor4=half_mirror∘quad_perm1B, xor8=row_ror:8) -- pure VALU
//   bits 8,9 : moved into registers by an LDS transpose (L2': regs k' =
//              {i9,i8,i1,i0}, lane = i[7:2]), then 2 in-reg stages.
// The transpose LDS round trip doubles as the staging needed for the random
// permutation gather. All LDS traffic is ds_{read,write}_b128 except the
// 16 random gather reads. Padding: addr(i) = i + 4*(i>>6) -- keeps every
// 4-word group 16B-aligned and makes the stride-16 b128 writes conflict-free
// (exactly 8 words/bank per instruction).

template <int CTRL>
__device__ __forceinline__ float dpp_f(float x) {
    return __int_as_float(
        __builtin_amdgcn_mov_dpp(__float_as_int(x), CTRL, 0xF, 0xF, true));
}

#define DPP_XOR1 0xB1   // quad_perm [1,0,3,2]
#define DPP_XOR2 0x4E   // quad_perm [2,3,0,1]
#define DPP_XOR3 0x1B   // quad_perm [3,2,1,0]
#define DPP_HMIR 0x141  // row_half_mirror: lane ^ 7
#define DPP_ROR8 0x128  // row_ror:8 == lane ^ 8 (rot by half = xor)

// Stages on bits 0-3 (reg index) + bits 4-7 (lane bits 0-3, DPP).
__device__ __forceinline__ void fwht_phaseA(float v[16], float sg0, float sg1,
                                            float sg2, float sg3) {
#pragma unroll
    for (int h = 1; h < 16; h <<= 1) {
#pragma unroll
        for (int k = 0; k < 16; ++k) {
            if (!(k & h)) {
                float a = v[k], b = v[k ^ h];
                v[k] = a + b;
                v[k ^ h] = a - b;
            }
        }
    }
#pragma unroll
    for (int k = 0; k < 16; ++k) v[k] = fmaf(v[k], sg0, dpp_f<DPP_XOR1>(v[k]));
#pragma unroll
    for (int k = 0; k < 16; ++k) v[k] = fmaf(v[k], sg1, dpp_f<DPP_XOR2>(v[k]));
#pragma unroll
    for (int k = 0; k < 16; ++k)
        v[k] = fmaf(v[k], sg2, dpp_f<DPP_XOR3>(dpp_f<DPP_HMIR>(v[k])));
#pragma unroll
    for (int k = 0; k < 16; ++k) v[k] = fmaf(v[k], sg3, dpp_f<DPP_ROR8>(v[k]));
}

// Stages on bits 8,9: in L2' regs, k'[2] = i8 (partner k'^4), k'[3] = i9 (k'^8).
__device__ __forceinline__ void fwht_phaseB(float v[16]) {
#pragma unroll
    for (int k = 0; k < 16; ++k) {
        if (!(k & 4)) { float a = v[k], b = v[k ^ 4]; v[k] = a + b; v[k ^ 4] = a - b; }
    }
#pragma unroll
    for (int k = 0; k < 16; ++k) {
        if (!(k & 8)) { float a = v[k], b = v[k ^ 8]; v[k] = a + b; v[k ^ 8] = a - b; }
    }
}

__global__ __launch_bounds__(256) void fastfood_kernel(
    const float* __restrict__ x, const float* __restrict__ B,
    const float* __restrict__ G, const float* __restrict__ S,
    const int* __restrict__ P, const float* __restrict__ u_rand,
    float* __restrict__ out)
{
    __shared__ float lds[4 * 1088];           // 4 waves * padded 1024
    const int lane = threadIdx.x & 63;
    const int wv   = threadIdx.x >> 6;
    const int row  = blockIdx.x * 4 + wv;

    const float sg0 = (lane & 1) ? -1.f : 1.f;
    const float sg1 = (lane & 2) ? -1.f : 1.f;
    const float sg2 = (lane & 4) ? -1.f : 1.f;
    const float sg3 = (lane & 8) ? -1.f : 1.f;

    float* wlds = lds + wv * 1088;
    // L1 padded write base for this lane: addr(16L) = 16L + 4*(L>>2)
    float4* w4L1 = (float4*)(wlds + 16 * lane + 4 * (lane >> 2));
    // L2' read/write addresses: i0 = b89*256 + 4L, addr = i0 + 4*(i0>>6)
    int addrL2[4];
#pragma unroll
    for (int b = 0; b < 4; ++b) {
        int i0 = b * 256 + 4 * lane;
        addrL2[b] = i0 + 4 * (i0 >> 6);
    }

    const float c_arg = 0.03125f * 0.15915494309189535f;  // (1/32)*(1/2pi)
    const float c_amp = 0.015625f;                        // sqrt(2/8192)

    // Load x row once (L1, coalesced float4)
    float xv[16];
    {
        const float4* x4 = (const float4*)(x + (size_t)row * 1024 + 16 * lane);
#pragma unroll
        for (int j = 0; j < 4; ++j) {
            float4 t = x4[j];
            xv[4 * j + 0] = t.x; xv[4 * j + 1] = t.y;
            xv[4 * j + 2] = t.z; xv[4 * j + 3] = t.w;
        }
    }

#pragma unroll 1
    for (int m = 0; m < 8; ++m) {
        const int mo = m * 1024;
        float v[16];

        // v = x * B[m]  (L1)
        {
            const float4* B4 = (const float4*)(B + mo + 16 * lane);
#pragma unroll
            for (int j = 0; j < 4; ++j) {
                float4 b = B4[j];
                v[4 * j + 0] = xv[4 * j + 0] * b.x;
                v[4 * j + 1] = xv[4 * j + 1] * b.y;
                v[4 * j + 2] = xv[4 * j + 2] * b.z;
                v[4 * j + 3] = xv[4 * j + 3] * b.w;
            }
        }

        // ---- FWHT #1 ----
        fwht_phaseA(v, sg0, sg1, sg2, sg3);
        // T1: write L1-contiguous (4x b128), read L2' (4x b128)
#pragma unroll
        for (int j = 0; j < 4; ++j)
            w4L1[j] = make_float4(v[4 * j + 0], v[4 * j + 1], v[4 * j + 2], v[4 * j + 3]);
#pragma unroll
        for (int b = 0; b < 4; ++b) {
            float4 t = *(const float4*)(wlds + addrL2[b]);
            v[4 * b + 0] = t.x; v[4 * b + 1] = t.y;
            v[4 * b + 2] = t.z; v[4 * b + 3] = t.w;
        }
        fwht_phaseB(v);

        // Staging write for the gather (L2' positions, 4x b128)
#pragma unroll
        for (int b = 0; b < 4; ++b)
            *(float4*)(wlds + addrL2[b]) =
                make_float4(v[4 * b + 0], v[4 * b + 1], v[4 * b + 2], v[4 * b + 3]);

        // Random gather (L1 target) * G
        {
            const int4*   P4 = (const int4*)(P + mo + 16 * lane);
            const float4* G4 = (const float4*)(G + mo + 16 * lane);
#pragma unroll
            for (int j = 0; j < 4; ++j) {
                int4 p = P4[j];
                float4 g = G4[j];
                v[4 * j + 0] = wlds[p.x + ((p.x >> 6) << 2)] * g.x;
                v[4 * j + 1] = wlds[p.y + ((p.y >> 6) << 2)] * g.y;
                v[4 * j + 2] = wlds[p.z + ((p.z >> 6) << 2)] * g.z;
                v[4 * j + 3] = wlds[p.w + ((p.w >> 6) << 2)] * g.w;
            }
        }

        // ---- FWHT #2 ----
        fwht_phaseA(v, sg0, sg1, sg2, sg3);
#pragma unroll
        for (int j = 0; j < 4; ++j)
            w4L1[j] = make_float4(v[4 * j + 0], v[4 * j + 1], v[4 * j + 2], v[4 * j + 3]);
#pragma unroll
        for (int b = 0; b < 4; ++b) {
            float4 t = *(const float4*)(wlds + addrL2[b]);
            v[4 * b + 0] = t.x; v[4 * b + 1] = t.y;
            v[4 * b + 2] = t.z; v[4 * b + 3] = t.w;
        }
        fwht_phaseB(v);

        // Epilogue in L2': element i = b*256 + 4*lane + c  -> float4 idx b*64+lane
        {
            const float4* S4 = (const float4*)(S + mo);
            const float4* U4 = (const float4*)(u_rand + mo);
            float4* o4 = (float4*)(out + (size_t)row * 8192 + mo);
#pragma unroll
            for (int b = 0; b < 4; ++b) {
                int idx = b * 64 + lane;
                float4 sv = S4[idx], uv = U4[idx], rr;
                rr.x = __builtin_amdgcn_cosf(__builtin_amdgcn_fractf(
                           fmaf(v[4 * b + 0] * sv.x, c_arg, uv.x))) * c_amp;
                rr.y = __builtin_amdgcn_cosf(__builtin_amdgcn_fractf(
                           fmaf(v[4 * b + 1] * sv.y, c_arg, uv.y))) * c_amp;
                rr.z = __builtin_amdgcn_cosf(__builtin_amdgcn_fractf(
                           fmaf(v[4 * b + 2] * sv.z, c_arg, uv.z))) * c_amp;
                rr.w = __builtin_amdgcn_cosf(__builtin_amdgcn_fractf(
                           fmaf(v[4 * b + 3] * sv.w, c_arg, uv.w))) * c_amp;
                o4[idx] = rr;
            }
        }
    }
}

extern "C" void kernel_launch(void* const* d_in, const int* in_sizes, int n_in,
                              void* d_out, int out_size, void* d_ws, size_t ws_size,
                              hipStream_t stream) {
    const float* x = (const float*)d_in[0];
    const float* B = (const float*)d_in[1];
    const float* G = (const float*)d_in[2];
    const float* S = (const float*)d_in[3];
    const int*   P = (const int*)d_in[4];
    const float* u = (const float*)d_in[5];
    float* out = (float*)d_out;

    dim3 grid(2048), block(256);
    hipLaunchKernelGGL(fastfood_kernel, grid, block, 0, stream,
                       x, B, G, S, P, u, out);
}